// Round 6
// baseline (580.639 us; speedup 1.0000x reference)
//
#include <hip/hip_runtime.h>

#define N_NODES 50000
#define N_EDGES 600000
#define N_GRAPHS 2048
#define EMB 128
#define TDIM 384
#define HN (N_NODES * EMB)
#define SCAN_NB ((N_NODES + 255) / 256)   // 196

typedef __attribute__((ext_vector_type(8))) short bf16x8;
typedef __attribute__((ext_vector_type(4))) float f32x4;
#define MFMA_BF16(a, b, c) __builtin_amdgcn_mfma_f32_16x16x32_bf16(a, b, c, 0, 0, 0)

__device__ inline unsigned short f2bf(float f) {
  unsigned int u = __float_as_uint(f);
  u += 0x7fffu + ((u >> 16) & 1u);   // round to nearest even
  return (unsigned short)(u >> 16);
}
__device__ inline float bf2f(unsigned short b) {
  return __uint_as_float(((unsigned int)b) << 16);
}

// ---------------- Atom encoder: h (fp32) + h_bf (bf16 shadow for gathers) ----------------
__global__ __launch_bounds__(128) void k_atom(const int* __restrict__ x,
                                              const float* __restrict__ atom_emb,
                                              float* __restrict__ h,
                                              unsigned short* __restrict__ h_bf) {
  int n = blockIdx.x, e = threadIdx.x;
  const int* xr = x + n * 9;
  float acc = 0.f;
#pragma unroll
  for (int c = 0; c < 9; ++c) acc += atom_emb[(c * 100 + xr[c]) * EMB + e];
  h[n * EMB + e] = acc;
  h_bf[n * EMB + e] = f2bf(acc);
}

// ---------------- CSR build ----------------
__global__ __launch_bounds__(256) void k_hist(const int* __restrict__ ei, int* __restrict__ deg) {
  int e = blockIdx.x * 256 + threadIdx.x;
  if (e < N_EDGES) atomicAdd(&deg[ei[N_EDGES + e]], 1);
}

__global__ __launch_bounds__(256) void k_scan_a(const int* __restrict__ deg,
                                                int* __restrict__ row_start,
                                                int* __restrict__ partials) {
  __shared__ int s[256];
  const int tid = threadIdx.x;
  const int i = blockIdx.x * 256 + tid;
  int v = (i < N_NODES) ? deg[i] : 0;
  s[tid] = v;
  __syncthreads();
  for (int off = 1; off < 256; off <<= 1) {
    int t = (tid >= off) ? s[tid - off] : 0;
    __syncthreads();
    s[tid] += t;
    __syncthreads();
  }
  if (i < N_NODES) row_start[i] = s[tid] - v;
  if (tid == 255) partials[blockIdx.x] = s[255];
}

__global__ __launch_bounds__(256) void k_scan_b(int* __restrict__ partials,
                                                int* __restrict__ row_start) {
  __shared__ int s[256];
  const int tid = threadIdx.x;
  int v = (tid < SCAN_NB) ? partials[tid] : 0;
  s[tid] = v;
  __syncthreads();
  for (int off = 1; off < 256; off <<= 1) {
    int t = (tid >= off) ? s[tid - off] : 0;
    __syncthreads();
    s[tid] += t;
    __syncthreads();
  }
  if (tid < SCAN_NB) partials[tid] = s[tid] - v;
  if (tid == 255) row_start[N_NODES] = s[255];
}

__global__ __launch_bounds__(256) void k_scan_c(int* __restrict__ row_start,
                                                const int* __restrict__ partials,
                                                int* __restrict__ cursor) {
  const int i = blockIdx.x * 256 + threadIdx.x;
  if (i < N_NODES) {
    int r = row_start[i] + partials[blockIdx.x];
    row_start[i] = r;
    cursor[i] = r;
  }
}

__global__ __launch_bounds__(256) void k_scatter(const int* __restrict__ ei,
                                                 const int* __restrict__ ea,
                                                 const float* __restrict__ bond_emb,
                                                 int* __restrict__ cursor,
                                                 int* __restrict__ sorted_src,
                                                 float4* __restrict__ sew) {
  int e = blockIdx.x * 256 + threadIdx.x;
  if (e >= N_EDGES) return;
  int src = ei[e], dst = ei[N_EDGES + e];
  int pos = atomicAdd(&cursor[dst], 1);
  sorted_src[pos] = src;
  int a0 = ea[e * 3 + 0], a1 = ea[e * 3 + 1], a2 = ea[e * 3 + 2];
#pragma unroll
  for (int layer = 0; layer < 3; ++layer) {
    const float* bl = bond_emb + layer * 72;
    float4 w;
    w.x = bl[a0 * 3 + 0] + bl[24 + a1 * 3 + 0] + bl[48 + a2 * 3 + 0];
    w.y = bl[a0 * 3 + 1] + bl[24 + a1 * 3 + 1] + bl[48 + a2 * 3 + 1];
    w.z = bl[a0 * 3 + 2] + bl[24 + a1 * 3 + 2] + bl[48 + a2 * 3 + 2];
    w.w = 0.f;
    sew[(size_t)layer * N_EDGES + pos] = w;
  }
}

// ---------------- W -> W_T split bf16: wt[(layer*128+c)*384 + k], k = conv*128 + j ----------------
__global__ __launch_bounds__(384) void k_wconv(const float* __restrict__ W,
                                               unsigned short* __restrict__ wt_hi,
                                               unsigned short* __restrict__ wt_lo) {
  int layer = blockIdx.x >> 7, c = blockIdx.x & 127, k = threadIdx.x;
  float v = W[(((layer * 3 + (k >> 7)) * 128) + (k & 127)) * 128 + c];
  unsigned short hi = f2bf(v);
  float rem = v - bf2f(hi);
  size_t idx = (size_t)blockIdx.x * 384 + k;
  wt_hi[idx] = hi;
  wt_lo[idx] = f2bf(rem);
}

// ---------------- Edge aggregation (bf16 gather, fp32 accum, bf16 t) ----------------
__global__ __launch_bounds__(256) void k_agg(const int* __restrict__ sorted_src,
                                             const float4* __restrict__ sew_l,
                                             const int* __restrict__ row_start,
                                             const unsigned short* __restrict__ h_bf,
                                             unsigned short* __restrict__ t_bf) {
  const int node = blockIdx.x * 4 + (threadIdx.x >> 6);
  const int lane = threadIdx.x & 63;
  const int beg = row_start[node], end = row_start[node + 1];
  float2 a0 = {0.f, 0.f}, a1 = {0.f, 0.f}, a2 = {0.f, 0.f};
  int e = beg;
  for (; e + 4 <= end; e += 4) {
    int s0 = sorted_src[e],     s1 = sorted_src[e + 1];
    int s2 = sorted_src[e + 2], s3 = sorted_src[e + 3];
    float4 w0 = sew_l[e],     w1 = sew_l[e + 1];
    float4 w2 = sew_l[e + 2], w3 = sew_l[e + 3];
    ushort2 u0 = *(const ushort2*)(h_bf + (size_t)s0 * EMB + lane * 2);
    ushort2 u1 = *(const ushort2*)(h_bf + (size_t)s1 * EMB + lane * 2);
    ushort2 u2 = *(const ushort2*)(h_bf + (size_t)s2 * EMB + lane * 2);
    ushort2 u3 = *(const ushort2*)(h_bf + (size_t)s3 * EMB + lane * 2);
    float2 v0 = {bf2f(u0.x), bf2f(u0.y)};
    float2 v1 = {bf2f(u1.x), bf2f(u1.y)};
    float2 v2 = {bf2f(u2.x), bf2f(u2.y)};
    float2 v3 = {bf2f(u3.x), bf2f(u3.y)};
    a0.x += w0.x * v0.x + w1.x * v1.x + w2.x * v2.x + w3.x * v3.x;
    a0.y += w0.x * v0.y + w1.x * v1.y + w2.x * v2.y + w3.x * v3.y;
    a1.x += w0.y * v0.x + w1.y * v1.x + w2.y * v2.x + w3.y * v3.x;
    a1.y += w0.y * v0.y + w1.y * v1.y + w2.y * v2.y + w3.y * v3.y;
    a2.x += w0.z * v0.x + w1.z * v1.x + w2.z * v2.x + w3.z * v3.x;
    a2.y += w0.z * v0.y + w1.z * v1.y + w2.z * v2.y + w3.z * v3.y;
  }
  for (; e < end; ++e) {
    int s = sorted_src[e];
    float4 w = sew_l[e];
    ushort2 u = *(const ushort2*)(h_bf + (size_t)s * EMB + lane * 2);
    float2 v = {bf2f(u.x), bf2f(u.y)};
    a0.x += w.x * v.x; a0.y += w.x * v.y;
    a1.x += w.y * v.x; a1.y += w.y * v.y;
    a2.x += w.z * v.x; a2.y += w.z * v.y;
  }
  size_t base = (size_t)node * TDIM + lane * 2;
  *(ushort2*)(t_bf + base)       = ushort2{f2bf(a0.x), f2bf(a0.y)};
  *(ushort2*)(t_bf + base + 128) = ushort2{f2bf(a1.x), f2bf(a1.y)};
  *(ushort2*)(t_bf + base + 256) = ushort2{f2bf(a2.x), f2bf(a2.y)};
}

// ---------------- MFMA GEMM + bias + relu + residual ----------------
// Wave: 16 rows x 64 cols (4 tiles). Block 256 = 4 waves -> 32 rows x 128 cols.
// Grid 1563 blocks = 6252 waves (~24 waves/CU). A (bf16 t) preloaded: 12 frags,
// B (split W) streamed from L2, 2 MFMAs per tile-k. No LDS.
// A-frag: A[m=lane&15][k=(lane>>4)*8+j]; B-frag: B[k][n=lane&15] same addressing
// off W_T rows; C/D: col=lane&15, row=(lane>>4)*4+reg.
__global__ __launch_bounds__(256) void k_mfma(const unsigned short* __restrict__ t_bf,
                                              const unsigned short* __restrict__ wt_hi,
                                              const unsigned short* __restrict__ wt_lo,
                                              const float* __restrict__ bl,  // [3][128]
                                              float* __restrict__ h,
                                              unsigned short* __restrict__ h_bf,
                                              int do_relu) {
  const int wv = threadIdx.x >> 6;
  const int lane = threadIdx.x & 63;
  const int r_base = blockIdx.x * 32 + (wv >> 1) * 16;
  const int c_base = (wv & 1) * 64;
  const int m = lane & 15;
  const int kq = lane >> 4;

  int rowA = r_base + m;
  if (rowA >= N_NODES) rowA = N_NODES - 1;
  const unsigned short* pA = t_bf + (size_t)rowA * TDIM + kq * 8;
  bf16x8 A[12];
#pragma unroll
  for (int kc = 0; kc < 12; ++kc) A[kc] = *(const bf16x8*)(pA + kc * 32);

  f32x4 acc[4];
  float bias[4];
#pragma unroll
  for (int ct = 0; ct < 4; ++ct) {
    acc[ct] = f32x4{0.f, 0.f, 0.f, 0.f};
    int c = c_base + ct * 16 + m;
    bias[ct] = bl[c] + bl[128 + c] + bl[256 + c];
  }

#pragma unroll
  for (int ct = 0; ct < 4; ++ct) {
    int c = c_base + ct * 16 + m;
    const unsigned short* pBh = wt_hi + (size_t)c * TDIM + kq * 8;
    const unsigned short* pBl = wt_lo + (size_t)c * TDIM + kq * 8;
#pragma unroll
    for (int kc = 0; kc < 12; ++kc) {
      bf16x8 Bh = *(const bf16x8*)(pBh + kc * 32);
      bf16x8 Bl = *(const bf16x8*)(pBl + kc * 32);
      acc[ct] = MFMA_BF16(A[kc], Bh, acc[ct]);
      acc[ct] = MFMA_BF16(A[kc], Bl, acc[ct]);
    }
  }

#pragma unroll
  for (int r = 0; r < 4; ++r) {
    int row = r_base + kq * 4 + r;
    if (row < N_NODES) {
#pragma unroll
      for (int ct = 0; ct < 4; ++ct) {
        int col = c_base + ct * 16 + m;
        size_t idx = (size_t)row * EMB + col;
        float v = acc[ct][r] + bias[ct];
        if (do_relu) v = fmaxf(v, 0.f);
        float hn = h[idx] + v;
        h[idx] = hn;
        h_bf[idx] = f2bf(hn);
      }
    }
  }
}

// ---------------- mean-pool: run-length segmented ----------------
__global__ __launch_bounds__(128) void k_pool(const float* __restrict__ h,
                                              const int* __restrict__ batch,
                                              float* __restrict__ sums,
                                              float* __restrict__ counts) {
  const int e = threadIdx.x;
  const int n0 = blockIdx.x * 32;
  int g_cur = -1, run = 0;
  float acc = 0.f;
  for (int i = 0; i < 32; ++i) {
    int n = n0 + i;
    if (n >= N_NODES) break;
    int g = batch[n];
    if (g != g_cur) {
      if (g_cur >= 0) {
        atomicAdd(&sums[g_cur * EMB + e], acc);
        if (e == 0) atomicAdd(&counts[g_cur], (float)run);
      }
      g_cur = g; acc = 0.f; run = 0;
    }
    acc += h[(size_t)n * EMB + e];
    ++run;
  }
  if (g_cur >= 0) {
    atomicAdd(&sums[g_cur * EMB + e], acc);
    if (e == 0) atomicAdd(&counts[g_cur], (float)run);
  }
}

// ---------------- head ----------------
__global__ __launch_bounds__(128) void k_head(const float* __restrict__ sums,
                                              const float* __restrict__ counts,
                                              const float* __restrict__ fc1_w,
                                              const float* __restrict__ fc1_b,
                                              const float* __restrict__ fc2_w,
                                              const float* __restrict__ fc2_b,
                                              float* __restrict__ out) {
  __shared__ float hg[EMB];
  __shared__ float red[EMB];
  int g = blockIdx.x, e = threadIdx.x;
  float cnt = fmaxf(counts[g], 1.f);
  hg[e] = sums[g * EMB + e] / cnt;
  __syncthreads();
  float acc = fc1_b[e];
  for (int j = 0; j < EMB; ++j) acc += hg[j] * fc1_w[j * EMB + e];
  red[e] = acc * fc2_w[e];
  __syncthreads();
  for (int s = 64; s > 0; s >>= 1) {
    if (e < s) red[e] += red[e + s];
    __syncthreads();
  }
  if (e == 0) out[g] = red[0] + fc2_b[0];
}

extern "C" void kernel_launch(void* const* d_in, const int* in_sizes, int n_in,
                              void* d_out, int out_size, void* d_ws, size_t ws_size,
                              hipStream_t stream) {
  const int*   x        = (const int*)d_in[0];
  const int*   ei       = (const int*)d_in[1];
  const int*   ea       = (const int*)d_in[2];
  const int*   batch    = (const int*)d_in[3];
  const float* atom_emb = (const float*)d_in[4];
  const float* bond_emb = (const float*)d_in[5];
  const float* W        = (const float*)d_in[6];
  const float* b        = (const float*)d_in[7];
  const float* fc1_w    = (const float*)d_in[8];
  const float* fc1_b    = (const float*)d_in[9];
  const float* fc2_w    = (const float*)d_in[10];
  const float* fc2_b    = (const float*)d_in[11];
  float* out = (float*)d_out;

  char* p = (char*)d_ws;
  auto alloc = [&](size_t bytes) { char* r = p; p += (bytes + 255) & ~(size_t)255; return r; };
  float*          h          = (float*)alloc((size_t)HN * 4);
  unsigned short* h_bf       = (unsigned short*)alloc((size_t)HN * 2);
  unsigned short* t_bf       = (unsigned short*)alloc((size_t)N_NODES * TDIM * 2);
  unsigned short* wt_hi      = (unsigned short*)alloc((size_t)3 * 128 * TDIM * 2);
  unsigned short* wt_lo      = (unsigned short*)alloc((size_t)3 * 128 * TDIM * 2);
  float*          sums       = (float*)alloc((size_t)N_GRAPHS * EMB * 4);
  float*          counts     = (float*)alloc((size_t)N_GRAPHS * 4);
  int*            deg        = (int*)alloc((size_t)N_NODES * 4);
  int*            row_start  = (int*)alloc((size_t)(N_NODES + 1) * 4);
  int*            cursor     = (int*)alloc((size_t)N_NODES * 4);
  int*            partials   = (int*)alloc(256 * 4);
  int*            sorted_src = (int*)alloc((size_t)N_EDGES * 4);
  float4*         sew        = (float4*)alloc((size_t)3 * N_EDGES * 16);

  hipMemsetAsync(deg, 0, N_NODES * sizeof(int), stream);
  k_atom<<<N_NODES, 128, 0, stream>>>(x, atom_emb, h, h_bf);
  k_hist<<<(N_EDGES + 255) / 256, 256, 0, stream>>>(ei, deg);
  k_scan_a<<<SCAN_NB, 256, 0, stream>>>(deg, row_start, partials);
  k_scan_b<<<1, 256, 0, stream>>>(partials, row_start);
  k_scan_c<<<SCAN_NB, 256, 0, stream>>>(row_start, partials, cursor);
  k_scatter<<<(N_EDGES + 255) / 256, 256, 0, stream>>>(ei, ea, bond_emb, cursor,
                                                       sorted_src, sew);
  k_wconv<<<3 * 128, 384, 0, stream>>>(W, wt_hi, wt_lo);

  const int gemm_blocks = (N_NODES + 31) / 32;  // 1563
  for (int layer = 0; layer < 3; ++layer) {
    k_agg<<<N_NODES / 4, 256, 0, stream>>>(sorted_src, sew + (size_t)layer * N_EDGES,
                                           row_start, h_bf, t_bf);
    k_mfma<<<gemm_blocks, 256, 0, stream>>>(
        t_bf, wt_hi + (size_t)layer * 128 * TDIM, wt_lo + (size_t)layer * 128 * TDIM,
        b + layer * 3 * EMB, h, h_bf, layer < 2 ? 1 : 0);
  }

  hipMemsetAsync(sums, 0, N_GRAPHS * EMB * sizeof(float), stream);
  hipMemsetAsync(counts, 0, N_GRAPHS * sizeof(float), stream);
  k_pool<<<(N_NODES + 31) / 32, 128, 0, stream>>>(h, batch, sums, counts);
  k_head<<<N_GRAPHS, 128, 0, stream>>>(sums, counts, fc1_w, fc1_b, fc2_w, fc2_b, out);
}

// Round 7
// 476.968 us; speedup vs baseline: 1.2174x; 1.2174x over previous
//
#include <hip/hip_runtime.h>

#define N_NODES 50000
#define N_EDGES 600000
#define N_GRAPHS 2048
#define EMB 128
#define TDIM 384
#define HN (N_NODES * EMB)
#define SCAN_NB ((N_NODES + 255) / 256)   // 196

typedef __attribute__((ext_vector_type(8))) short bf16x8;
typedef __attribute__((ext_vector_type(4))) float f32x4;
#define MFMA_BF16(a, b, c) __builtin_amdgcn_mfma_f32_16x16x32_bf16(a, b, c, 0, 0, 0)

__device__ inline unsigned short f2bf(float f) {
  unsigned int u = __float_as_uint(f);
  u += 0x7fffu + ((u >> 16) & 1u);   // round to nearest even
  return (unsigned short)(u >> 16);
}
__device__ inline float bf2f(unsigned short b) {
  return __uint_as_float(((unsigned int)b) << 16);
}

// ---------------- Atom encoder: h (fp32) + h_bf (bf16 shadow for gathers) ----------------
__global__ __launch_bounds__(128) void k_atom(const int* __restrict__ x,
                                              const float* __restrict__ atom_emb,
                                              float* __restrict__ h,
                                              unsigned short* __restrict__ h_bf) {
  int n = blockIdx.x, e = threadIdx.x;
  const int* xr = x + n * 9;
  float acc = 0.f;
#pragma unroll
  for (int c = 0; c < 9; ++c) acc += atom_emb[(c * 100 + xr[c]) * EMB + e];
  h[n * EMB + e] = acc;
  h_bf[n * EMB + e] = f2bf(acc);
}

// ---------------- CSR build ----------------
__global__ __launch_bounds__(256) void k_hist(const int* __restrict__ ei, int* __restrict__ deg) {
  int e = blockIdx.x * 256 + threadIdx.x;
  if (e < N_EDGES) atomicAdd(&deg[ei[N_EDGES + e]], 1);
}

__global__ __launch_bounds__(256) void k_scan_a(const int* __restrict__ deg,
                                                int* __restrict__ row_start,
                                                int* __restrict__ partials) {
  __shared__ int s[256];
  const int tid = threadIdx.x;
  const int i = blockIdx.x * 256 + tid;
  int v = (i < N_NODES) ? deg[i] : 0;
  s[tid] = v;
  __syncthreads();
  for (int off = 1; off < 256; off <<= 1) {
    int t = (tid >= off) ? s[tid - off] : 0;
    __syncthreads();
    s[tid] += t;
    __syncthreads();
  }
  if (i < N_NODES) row_start[i] = s[tid] - v;
  if (tid == 255) partials[blockIdx.x] = s[255];
}

__global__ __launch_bounds__(256) void k_scan_b(int* __restrict__ partials,
                                                int* __restrict__ row_start) {
  __shared__ int s[256];
  const int tid = threadIdx.x;
  int v = (tid < SCAN_NB) ? partials[tid] : 0;
  s[tid] = v;
  __syncthreads();
  for (int off = 1; off < 256; off <<= 1) {
    int t = (tid >= off) ? s[tid - off] : 0;
    __syncthreads();
    s[tid] += t;
    __syncthreads();
  }
  if (tid < SCAN_NB) partials[tid] = s[tid] - v;
  if (tid == 255) row_start[N_NODES] = s[255];
}

__global__ __launch_bounds__(256) void k_scan_c(int* __restrict__ row_start,
                                                const int* __restrict__ partials,
                                                int* __restrict__ cursor) {
  const int i = blockIdx.x * 256 + threadIdx.x;
  if (i < N_NODES) {
    int r = row_start[i] + partials[blockIdx.x];
    row_start[i] = r;
    cursor[i] = r;
  }
}

__global__ __launch_bounds__(256) void k_scatter(const int* __restrict__ ei,
                                                 const int* __restrict__ ea,
                                                 const float* __restrict__ bond_emb,
                                                 int* __restrict__ cursor,
                                                 int* __restrict__ sorted_src,
                                                 float4* __restrict__ sew) {
  int e = blockIdx.x * 256 + threadIdx.x;
  if (e >= N_EDGES) return;
  int src = ei[e], dst = ei[N_EDGES + e];
  int pos = atomicAdd(&cursor[dst], 1);
  sorted_src[pos] = src;
  int a0 = ea[e * 3 + 0], a1 = ea[e * 3 + 1], a2 = ea[e * 3 + 2];
#pragma unroll
  for (int layer = 0; layer < 3; ++layer) {
    const float* bl = bond_emb + layer * 72;
    float4 w;
    w.x = bl[a0 * 3 + 0] + bl[24 + a1 * 3 + 0] + bl[48 + a2 * 3 + 0];
    w.y = bl[a0 * 3 + 1] + bl[24 + a1 * 3 + 1] + bl[48 + a2 * 3 + 1];
    w.z = bl[a0 * 3 + 2] + bl[24 + a1 * 3 + 2] + bl[48 + a2 * 3 + 2];
    w.w = 0.f;
    sew[(size_t)layer * N_EDGES + pos] = w;
  }
}

// ---------------- W -> W_T bf16: wt[(layer*128+c)*384 + k], k = conv*128 + j ----------------
__global__ __launch_bounds__(384) void k_wconv(const float* __restrict__ W,
                                               unsigned short* __restrict__ wt) {
  int layer = blockIdx.x >> 7, c = blockIdx.x & 127, k = threadIdx.x;
  float v = W[(((layer * 3 + (k >> 7)) * 128) + (k & 127)) * 128 + c];
  wt[(size_t)blockIdx.x * 384 + k] = f2bf(v);
}

// ---------------- Edge aggregation (bf16 gather, fp32 accum, bf16 t) ----------------
__global__ __launch_bounds__(256) void k_agg(const int* __restrict__ sorted_src,
                                             const float4* __restrict__ sew_l,
                                             const int* __restrict__ row_start,
                                             const unsigned short* __restrict__ h_bf,
                                             unsigned short* __restrict__ t_bf) {
  const int node = blockIdx.x * 4 + (threadIdx.x >> 6);
  const int lane = threadIdx.x & 63;
  const int beg = row_start[node], end = row_start[node + 1];
  float2 a0 = {0.f, 0.f}, a1 = {0.f, 0.f}, a2 = {0.f, 0.f};
  int e = beg;
  for (; e + 4 <= end; e += 4) {
    int s0 = sorted_src[e],     s1 = sorted_src[e + 1];
    int s2 = sorted_src[e + 2], s3 = sorted_src[e + 3];
    float4 w0 = sew_l[e],     w1 = sew_l[e + 1];
    float4 w2 = sew_l[e + 2], w3 = sew_l[e + 3];
    ushort2 u0 = *(const ushort2*)(h_bf + (size_t)s0 * EMB + lane * 2);
    ushort2 u1 = *(const ushort2*)(h_bf + (size_t)s1 * EMB + lane * 2);
    ushort2 u2 = *(const ushort2*)(h_bf + (size_t)s2 * EMB + lane * 2);
    ushort2 u3 = *(const ushort2*)(h_bf + (size_t)s3 * EMB + lane * 2);
    float2 v0 = {bf2f(u0.x), bf2f(u0.y)};
    float2 v1 = {bf2f(u1.x), bf2f(u1.y)};
    float2 v2 = {bf2f(u2.x), bf2f(u2.y)};
    float2 v3 = {bf2f(u3.x), bf2f(u3.y)};
    a0.x += w0.x * v0.x + w1.x * v1.x + w2.x * v2.x + w3.x * v3.x;
    a0.y += w0.x * v0.y + w1.x * v1.y + w2.x * v2.y + w3.x * v3.y;
    a1.x += w0.y * v0.x + w1.y * v1.x + w2.y * v2.x + w3.y * v3.x;
    a1.y += w0.y * v0.y + w1.y * v1.y + w2.y * v2.y + w3.y * v3.y;
    a2.x += w0.z * v0.x + w1.z * v1.x + w2.z * v2.x + w3.z * v3.x;
    a2.y += w0.z * v0.y + w1.z * v1.y + w2.z * v2.y + w3.z * v3.y;
  }
  for (; e < end; ++e) {
    int s = sorted_src[e];
    float4 w = sew_l[e];
    ushort2 u = *(const ushort2*)(h_bf + (size_t)s * EMB + lane * 2);
    float2 v = {bf2f(u.x), bf2f(u.y)};
    a0.x += w.x * v.x; a0.y += w.x * v.y;
    a1.x += w.y * v.x; a1.y += w.y * v.y;
    a2.x += w.z * v.x; a2.y += w.z * v.y;
  }
  size_t base = (size_t)node * TDIM + lane * 2;
  *(ushort2*)(t_bf + base)       = ushort2{f2bf(a0.x), f2bf(a0.y)};
  *(ushort2*)(t_bf + base + 128) = ushort2{f2bf(a1.x), f2bf(a1.y)};
  *(ushort2*)(t_bf + base + 256) = ushort2{f2bf(a2.x), f2bf(a2.y)};
}

// ---------------- MFMA GEMM + bias + relu + residual ----------------
// Wave = 16 cols x 128 rows. B-frags (12) loaded ONCE, register-resident;
// A streams 8 row-tiles (12 frags each) with inline epilogue (acc only 4 regs).
// Block 256 = 4 waves -> 64 cols; grid (391, 2) covers 50048 rows x 128 cols.
// A-frag: A[m=lane&15][k=(lane>>4)*8+j]; B-frag: B[k][n=lane&15];
// C/D: col=lane&15, row=(lane>>4)*4+reg.
__global__ __launch_bounds__(256) void k_mfma(const unsigned short* __restrict__ t_bf,
                                              const unsigned short* __restrict__ wt,
                                              const float* __restrict__ bl,  // [3][128]
                                              float* __restrict__ h,
                                              unsigned short* __restrict__ h_bf,
                                              int do_relu) {
  const int wv = threadIdx.x >> 6;
  const int lane = threadIdx.x & 63;
  const int m = lane & 15;
  const int kq = lane >> 4;
  const int r_base = blockIdx.x * 128;
  const int c = blockIdx.y * 64 + wv * 16 + m;

  // resident B fragments for this wave's 16-column tile
  const unsigned short* pB = wt + (size_t)c * TDIM + kq * 8;
  bf16x8 B[12];
#pragma unroll
  for (int kc = 0; kc < 12; ++kc) B[kc] = *(const bf16x8*)(pB + kc * 32);

  const float bias = bl[c] + bl[128 + c] + bl[256 + c];

#pragma unroll 2
  for (int rt = 0; rt < 8; ++rt) {
    const int row0 = r_base + rt * 16;
    if (row0 >= N_NODES) continue;
    int rowA = row0 + m;
    if (rowA >= N_NODES) rowA = N_NODES - 1;
    const unsigned short* pA = t_bf + (size_t)rowA * TDIM + kq * 8;
    bf16x8 A[12];
#pragma unroll
    for (int kc = 0; kc < 12; ++kc) A[kc] = *(const bf16x8*)(pA + kc * 32);
    f32x4 acc = {0.f, 0.f, 0.f, 0.f};
#pragma unroll
    for (int kc = 0; kc < 12; ++kc) acc = MFMA_BF16(A[kc], B[kc], acc);
#pragma unroll
    for (int r = 0; r < 4; ++r) {
      int row = row0 + kq * 4 + r;
      if (row < N_NODES) {
        size_t idx = (size_t)row * EMB + c;
        float v = acc[r] + bias;
        if (do_relu) v = fmaxf(v, 0.f);
        float hn = h[idx] + v;
        h[idx] = hn;
        h_bf[idx] = f2bf(hn);
      }
    }
  }
}

// ---------------- mean-pool: run-length segmented ----------------
__global__ __launch_bounds__(128) void k_pool(const float* __restrict__ h,
                                              const int* __restrict__ batch,
                                              float* __restrict__ sums,
                                              float* __restrict__ counts) {
  const int e = threadIdx.x;
  const int n0 = blockIdx.x * 32;
  int g_cur = -1, run = 0;
  float acc = 0.f;
  for (int i = 0; i < 32; ++i) {
    int n = n0 + i;
    if (n >= N_NODES) break;
    int g = batch[n];
    if (g != g_cur) {
      if (g_cur >= 0) {
        atomicAdd(&sums[g_cur * EMB + e], acc);
        if (e == 0) atomicAdd(&counts[g_cur], (float)run);
      }
      g_cur = g; acc = 0.f; run = 0;
    }
    acc += h[(size_t)n * EMB + e];
    ++run;
  }
  if (g_cur >= 0) {
    atomicAdd(&sums[g_cur * EMB + e], acc);
    if (e == 0) atomicAdd(&counts[g_cur], (float)run);
  }
}

// ---------------- head ----------------
__global__ __launch_bounds__(128) void k_head(const float* __restrict__ sums,
                                              const float* __restrict__ counts,
                                              const float* __restrict__ fc1_w,
                                              const float* __restrict__ fc1_b,
                                              const float* __restrict__ fc2_w,
                                              const float* __restrict__ fc2_b,
                                              float* __restrict__ out) {
  __shared__ float hg[EMB];
  __shared__ float red[EMB];
  int g = blockIdx.x, e = threadIdx.x;
  float cnt = fmaxf(counts[g], 1.f);
  hg[e] = sums[g * EMB + e] / cnt;
  __syncthreads();
  float acc = fc1_b[e];
  for (int j = 0; j < EMB; ++j) acc += hg[j] * fc1_w[j * EMB + e];
  red[e] = acc * fc2_w[e];
  __syncthreads();
  for (int s = 64; s > 0; s >>= 1) {
    if (e < s) red[e] += red[e + s];
    __syncthreads();
  }
  if (e == 0) out[g] = red[0] + fc2_b[0];
}

extern "C" void kernel_launch(void* const* d_in, const int* in_sizes, int n_in,
                              void* d_out, int out_size, void* d_ws, size_t ws_size,
                              hipStream_t stream) {
  const int*   x        = (const int*)d_in[0];
  const int*   ei       = (const int*)d_in[1];
  const int*   ea       = (const int*)d_in[2];
  const int*   batch    = (const int*)d_in[3];
  const float* atom_emb = (const float*)d_in[4];
  const float* bond_emb = (const float*)d_in[5];
  const float* W        = (const float*)d_in[6];
  const float* b        = (const float*)d_in[7];
  const float* fc1_w    = (const float*)d_in[8];
  const float* fc1_b    = (const float*)d_in[9];
  const float* fc2_w    = (const float*)d_in[10];
  const float* fc2_b    = (const float*)d_in[11];
  float* out = (float*)d_out;

  char* p = (char*)d_ws;
  auto alloc = [&](size_t bytes) { char* r = p; p += (bytes + 255) & ~(size_t)255; return r; };
  float*          h          = (float*)alloc((size_t)HN * 4);
  unsigned short* h_bf       = (unsigned short*)alloc((size_t)HN * 2);
  unsigned short* t_bf       = (unsigned short*)alloc((size_t)N_NODES * TDIM * 2);
  unsigned short* wt         = (unsigned short*)alloc((size_t)3 * 128 * TDIM * 2);
  float*          sums       = (float*)alloc((size_t)N_GRAPHS * EMB * 4);
  float*          counts     = (float*)alloc((size_t)N_GRAPHS * 4);
  int*            deg        = (int*)alloc((size_t)N_NODES * 4);
  int*            row_start  = (int*)alloc((size_t)(N_NODES + 1) * 4);
  int*            cursor     = (int*)alloc((size_t)N_NODES * 4);
  int*            partials   = (int*)alloc(256 * 4);
  int*            sorted_src = (int*)alloc((size_t)N_EDGES * 4);
  float4*         sew        = (float4*)alloc((size_t)3 * N_EDGES * 16);

  hipMemsetAsync(deg, 0, N_NODES * sizeof(int), stream);
  k_atom<<<N_NODES, 128, 0, stream>>>(x, atom_emb, h, h_bf);
  k_hist<<<(N_EDGES + 255) / 256, 256, 0, stream>>>(ei, deg);
  k_scan_a<<<SCAN_NB, 256, 0, stream>>>(deg, row_start, partials);
  k_scan_b<<<1, 256, 0, stream>>>(partials, row_start);
  k_scan_c<<<SCAN_NB, 256, 0, stream>>>(row_start, partials, cursor);
  k_scatter<<<(N_EDGES + 255) / 256, 256, 0, stream>>>(ei, ea, bond_emb, cursor,
                                                       sorted_src, sew);
  k_wconv<<<3 * 128, 384, 0, stream>>>(W, wt);

  const dim3 gemm_grid((N_NODES + 127) / 128, 2);  // 391 x 2
  for (int layer = 0; layer < 3; ++layer) {
    k_agg<<<N_NODES / 4, 256, 0, stream>>>(sorted_src, sew + (size_t)layer * N_EDGES,
                                           row_start, h_bf, t_bf);
    k_mfma<<<gemm_grid, 256, 0, stream>>>(
        t_bf, wt + (size_t)layer * 128 * TDIM,
        b + layer * 3 * EMB, h, h_bf, layer < 2 ? 1 : 0);
  }

  hipMemsetAsync(sums, 0, N_GRAPHS * EMB * sizeof(float), stream);
  hipMemsetAsync(counts, 0, N_GRAPHS * sizeof(float), stream);
  k_pool<<<(N_NODES + 31) / 32, 128, 0, stream>>>(h, batch, sums, counts);
  k_head<<<N_GRAPHS, 128, 0, stream>>>(sums, counts, fc1_w, fc1_b, fc2_w, fc2_b, out);
}

// Round 8
// 469.024 us; speedup vs baseline: 1.2380x; 1.0169x over previous
//
#include <hip/hip_runtime.h>

#define N_NODES 50000
#define N_EDGES 600000
#define N_GRAPHS 2048
#define EMB 128
#define TDIM 384
#define HN (N_NODES * EMB)
#define SCAN_NB ((N_NODES + 255) / 256)   // 196

typedef __attribute__((ext_vector_type(8))) short bf16x8;
typedef __attribute__((ext_vector_type(4))) float f32x4;
#define MFMA_BF16(a, b, c) __builtin_amdgcn_mfma_f32_16x16x32_bf16(a, b, c, 0, 0, 0)

__device__ inline unsigned short f2bf(float f) {
  unsigned int u = __float_as_uint(f);
  u += 0x7fffu + ((u >> 16) & 1u);   // round to nearest even
  return (unsigned short)(u >> 16);
}
__device__ inline float bf2f(unsigned short b) {
  return __uint_as_float(((unsigned int)b) << 16);
}

// ---------------- Atom encoder: h (fp32) + h_bf (bf16 shadow for gathers) ----------------
__global__ __launch_bounds__(128) void k_atom(const int* __restrict__ x,
                                              const float* __restrict__ atom_emb,
                                              float* __restrict__ h,
                                              unsigned short* __restrict__ h_bf) {
  int n = blockIdx.x, e = threadIdx.x;
  const int* xr = x + n * 9;
  float acc = 0.f;
#pragma unroll
  for (int c = 0; c < 9; ++c) acc += atom_emb[(c * 100 + xr[c]) * EMB + e];
  h[n * EMB + e] = acc;
  h_bf[n * EMB + e] = f2bf(acc);
}

// ---------------- CSR build ----------------
__global__ __launch_bounds__(256) void k_hist(const int* __restrict__ ei, int* __restrict__ deg) {
  int e = blockIdx.x * 256 + threadIdx.x;
  if (e < N_EDGES) atomicAdd(&deg[ei[N_EDGES + e]], 1);
}

__global__ __launch_bounds__(256) void k_scan_a(const int* __restrict__ deg,
                                                int* __restrict__ row_start,
                                                int* __restrict__ partials) {
  __shared__ int s[256];
  const int tid = threadIdx.x;
  const int i = blockIdx.x * 256 + tid;
  int v = (i < N_NODES) ? deg[i] : 0;
  s[tid] = v;
  __syncthreads();
  for (int off = 1; off < 256; off <<= 1) {
    int t = (tid >= off) ? s[tid - off] : 0;
    __syncthreads();
    s[tid] += t;
    __syncthreads();
  }
  if (i < N_NODES) row_start[i] = s[tid] - v;
  if (tid == 255) partials[blockIdx.x] = s[255];
}

__global__ __launch_bounds__(256) void k_scan_b(int* __restrict__ partials,
                                                int* __restrict__ row_start) {
  __shared__ int s[256];
  const int tid = threadIdx.x;
  int v = (tid < SCAN_NB) ? partials[tid] : 0;
  s[tid] = v;
  __syncthreads();
  for (int off = 1; off < 256; off <<= 1) {
    int t = (tid >= off) ? s[tid - off] : 0;
    __syncthreads();
    s[tid] += t;
    __syncthreads();
  }
  if (tid < SCAN_NB) partials[tid] = s[tid] - v;
  if (tid == 255) row_start[N_NODES] = s[255];
}

__global__ __launch_bounds__(256) void k_scan_c(int* __restrict__ row_start,
                                                const int* __restrict__ partials,
                                                int* __restrict__ cursor) {
  const int i = blockIdx.x * 256 + threadIdx.x;
  if (i < N_NODES) {
    int r = row_start[i] + partials[blockIdx.x];
    row_start[i] = r;
    cursor[i] = r;
  }
}

// Scatter edges into CSR order: one int2{src, packed_attr} per edge.
__global__ __launch_bounds__(256) void k_scatter(const int* __restrict__ ei,
                                                 const int* __restrict__ ea,
                                                 int* __restrict__ cursor,
                                                 int2* __restrict__ sorted_se) {
  int e = blockIdx.x * 256 + threadIdx.x;
  if (e >= N_EDGES) return;
  int src = ei[e], dst = ei[N_EDGES + e];
  int pos = atomicAdd(&cursor[dst], 1);
  int eap = ea[e * 3 + 0] | (ea[e * 3 + 1] << 3) | (ea[e * 3 + 2] << 6);
  sorted_se[pos] = int2{src, eap};
}

// ---------------- W -> W_T bf16: wt[(layer*128+c)*384 + k], k = conv*128 + j ----------------
__global__ __launch_bounds__(384) void k_wconv(const float* __restrict__ W,
                                               unsigned short* __restrict__ wt) {
  int layer = blockIdx.x >> 7, c = blockIdx.x & 127, k = threadIdx.x;
  float v = W[(((layer * 3 + (k >> 7)) * 128) + (k & 127)) * 128 + c];
  wt[(size_t)blockIdx.x * 384 + k] = f2bf(v);
}

// ---------------- Edge aggregation (bf16 gather, LDS combo weights, clamped unroll-8) ----------------
__global__ __launch_bounds__(256) void k_agg(const int2* __restrict__ sorted_se,
                                             const int* __restrict__ row_start,
                                             const float* __restrict__ bl,  // bond_emb[layer]: [3][8][3]
                                             const unsigned short* __restrict__ h_bf,
                                             unsigned short* __restrict__ t_bf) {
  __shared__ float4 combo[512];  // 8 KB: ew for every packed (a0,a1,a2)
  for (int c = threadIdx.x; c < 512; c += 256) {
    int a0 = c & 7, a1 = (c >> 3) & 7, a2 = (c >> 6) & 7;
    combo[c] = float4{bl[a0 * 3 + 0] + bl[24 + a1 * 3 + 0] + bl[48 + a2 * 3 + 0],
                      bl[a0 * 3 + 1] + bl[24 + a1 * 3 + 1] + bl[48 + a2 * 3 + 1],
                      bl[a0 * 3 + 2] + bl[24 + a1 * 3 + 2] + bl[48 + a2 * 3 + 2], 0.f};
  }
  __syncthreads();
  const int node = blockIdx.x * 4 + (threadIdx.x >> 6);
  const int lane = threadIdx.x & 63;
  const int beg = row_start[node], end = row_start[node + 1];
  float2 a0 = {0.f, 0.f}, a1 = {0.f, 0.f}, a2 = {0.f, 0.f};
  for (int e = beg; e < end; e += 8) {
    int2 se[8];
#pragma unroll
    for (int i = 0; i < 8; ++i) {
      int idx = e + i;
      se[i] = sorted_se[idx < end ? idx : end - 1];
    }
    ushort2 u[8];
#pragma unroll
    for (int i = 0; i < 8; ++i)
      u[i] = *(const ushort2*)(h_bf + (size_t)se[i].x * EMB + lane * 2);
#pragma unroll
    for (int i = 0; i < 8; ++i) {
      float4 w = (e + i < end) ? combo[se[i].y] : float4{0.f, 0.f, 0.f, 0.f};
      float vx = bf2f(u[i].x), vy = bf2f(u[i].y);
      a0.x += w.x * vx; a0.y += w.x * vy;
      a1.x += w.y * vx; a1.y += w.y * vy;
      a2.x += w.z * vx; a2.y += w.z * vy;
    }
  }
  size_t base = (size_t)node * TDIM + lane * 2;
  *(ushort2*)(t_bf + base)       = ushort2{f2bf(a0.x), f2bf(a0.y)};
  *(ushort2*)(t_bf + base + 128) = ushort2{f2bf(a1.x), f2bf(a1.y)};
  *(ushort2*)(t_bf + base + 256) = ushort2{f2bf(a2.x), f2bf(a2.y)};
}

// ---------------- MFMA GEMM + bias + relu + residual ----------------
// Wave = 16 cols x 64 rows (4 row-tiles). B-frags (12) register-resident.
// Block 256 = 4 waves -> 64 cols; grid (782, 2). ~24 waves/CU.
// A-frag: A[m=lane&15][k=(lane>>4)*8+j]; B-frag: B[k][n=lane&15];
// C/D: col=lane&15, row=(lane>>4)*4+reg.
__global__ __launch_bounds__(256) void k_mfma(const unsigned short* __restrict__ t_bf,
                                              const unsigned short* __restrict__ wt,
                                              const float* __restrict__ bl,  // [3][128]
                                              float* __restrict__ h,
                                              unsigned short* __restrict__ h_bf,
                                              int do_relu, int write_bf) {
  const int wv = threadIdx.x >> 6;
  const int lane = threadIdx.x & 63;
  const int m = lane & 15;
  const int kq = lane >> 4;
  const int r_base = blockIdx.x * 64;
  const int c = blockIdx.y * 64 + wv * 16 + m;

  const unsigned short* pB = wt + (size_t)c * TDIM + kq * 8;
  bf16x8 B[12];
#pragma unroll
  for (int kc = 0; kc < 12; ++kc) B[kc] = *(const bf16x8*)(pB + kc * 32);

  const float bias = bl[c] + bl[128 + c] + bl[256 + c];

#pragma unroll 2
  for (int rt = 0; rt < 4; ++rt) {
    const int row0 = r_base + rt * 16;
    if (row0 >= N_NODES) continue;
    int rowA = row0 + m;
    if (rowA >= N_NODES) rowA = N_NODES - 1;
    const unsigned short* pA = t_bf + (size_t)rowA * TDIM + kq * 8;
    bf16x8 A[12];
#pragma unroll
    for (int kc = 0; kc < 12; ++kc) A[kc] = *(const bf16x8*)(pA + kc * 32);
    f32x4 acc = {0.f, 0.f, 0.f, 0.f};
#pragma unroll
    for (int kc = 0; kc < 12; ++kc) acc = MFMA_BF16(A[kc], B[kc], acc);
#pragma unroll
    for (int r = 0; r < 4; ++r) {
      int row = row0 + kq * 4 + r;
      if (row < N_NODES) {
        size_t idx = (size_t)row * EMB + c;
        float v = acc[r] + bias;
        if (do_relu) v = fmaxf(v, 0.f);
        float hn = h[idx] + v;
        h[idx] = hn;
        if (write_bf) h_bf[idx] = f2bf(hn);
      }
    }
  }
}

// ---------------- mean-pool: run-length segmented ----------------
__global__ __launch_bounds__(128) void k_pool(const float* __restrict__ h,
                                              const int* __restrict__ batch,
                                              float* __restrict__ sums,
                                              float* __restrict__ counts) {
  const int e = threadIdx.x;
  const int n0 = blockIdx.x * 32;
  int g_cur = -1, run = 0;
  float acc = 0.f;
  for (int i = 0; i < 32; ++i) {
    int n = n0 + i;
    if (n >= N_NODES) break;
    int g = batch[n];
    if (g != g_cur) {
      if (g_cur >= 0) {
        atomicAdd(&sums[g_cur * EMB + e], acc);
        if (e == 0) atomicAdd(&counts[g_cur], (float)run);
      }
      g_cur = g; acc = 0.f; run = 0;
    }
    acc += h[(size_t)n * EMB + e];
    ++run;
  }
  if (g_cur >= 0) {
    atomicAdd(&sums[g_cur * EMB + e], acc);
    if (e == 0) atomicAdd(&counts[g_cur], (float)run);
  }
}

// ---------------- head ----------------
__global__ __launch_bounds__(128) void k_head(const float* __restrict__ sums,
                                              const float* __restrict__ counts,
                                              const float* __restrict__ fc1_w,
                                              const float* __restrict__ fc1_b,
                                              const float* __restrict__ fc2_w,
                                              const float* __restrict__ fc2_b,
                                              float* __restrict__ out) {
  __shared__ float hg[EMB];
  __shared__ float red[EMB];
  int g = blockIdx.x, e = threadIdx.x;
  float cnt = fmaxf(counts[g], 1.f);
  hg[e] = sums[g * EMB + e] / cnt;
  __syncthreads();
  float acc = fc1_b[e];
  for (int j = 0; j < EMB; ++j) acc += hg[j] * fc1_w[j * EMB + e];
  red[e] = acc * fc2_w[e];
  __syncthreads();
  for (int s = 64; s > 0; s >>= 1) {
    if (e < s) red[e] += red[e + s];
    __syncthreads();
  }
  if (e == 0) out[g] = red[0] + fc2_b[0];
}

extern "C" void kernel_launch(void* const* d_in, const int* in_sizes, int n_in,
                              void* d_out, int out_size, void* d_ws, size_t ws_size,
                              hipStream_t stream) {
  const int*   x        = (const int*)d_in[0];
  const int*   ei       = (const int*)d_in[1];
  const int*   ea       = (const int*)d_in[2];
  const int*   batch    = (const int*)d_in[3];
  const float* atom_emb = (const float*)d_in[4];
  const float* bond_emb = (const float*)d_in[5];
  const float* W        = (const float*)d_in[6];
  const float* b        = (const float*)d_in[7];
  const float* fc1_w    = (const float*)d_in[8];
  const float* fc1_b    = (const float*)d_in[9];
  const float* fc2_w    = (const float*)d_in[10];
  const float* fc2_b    = (const float*)d_in[11];
  float* out = (float*)d_out;

  char* p = (char*)d_ws;
  auto alloc = [&](size_t bytes) { char* r = p; p += (bytes + 255) & ~(size_t)255; return r; };
  float*          h          = (float*)alloc((size_t)HN * 4);
  unsigned short* h_bf       = (unsigned short*)alloc((size_t)HN * 2);
  unsigned short* t_bf       = (unsigned short*)alloc((size_t)N_NODES * TDIM * 2);
  unsigned short* wt         = (unsigned short*)alloc((size_t)3 * 128 * TDIM * 2);
  float*          sums       = (float*)alloc((size_t)N_GRAPHS * EMB * 4);
  float*          counts     = (float*)alloc((size_t)N_GRAPHS * 4);
  int*            deg        = (int*)alloc((size_t)N_NODES * 4);
  int*            row_start  = (int*)alloc((size_t)(N_NODES + 1) * 4);
  int*            cursor     = (int*)alloc((size_t)N_NODES * 4);
  int*            partials   = (int*)alloc(256 * 4);
  int2*           sorted_se  = (int2*)alloc((size_t)N_EDGES * 8);

  hipMemsetAsync(deg, 0, N_NODES * sizeof(int), stream);
  k_atom<<<N_NODES, 128, 0, stream>>>(x, atom_emb, h, h_bf);
  k_hist<<<(N_EDGES + 255) / 256, 256, 0, stream>>>(ei, deg);
  k_scan_a<<<SCAN_NB, 256, 0, stream>>>(deg, row_start, partials);
  k_scan_b<<<1, 256, 0, stream>>>(partials, row_start);
  k_scan_c<<<SCAN_NB, 256, 0, stream>>>(row_start, partials, cursor);
  k_scatter<<<(N_EDGES + 255) / 256, 256, 0, stream>>>(ei, ea, cursor, sorted_se);
  k_wconv<<<3 * 128, 384, 0, stream>>>(W, wt);

  const dim3 gemm_grid((N_NODES + 63) / 64, 2);  // 782 x 2
  for (int layer = 0; layer < 3; ++layer) {
    k_agg<<<N_NODES / 4, 256, 0, stream>>>(sorted_se, row_start, bond_emb + layer * 72,
                                           h_bf, t_bf);
    k_mfma<<<gemm_grid, 256, 0, stream>>>(
        t_bf, wt + (size_t)layer * 128 * TDIM,
        b + layer * 3 * EMB, h, h_bf, layer < 2 ? 1 : 0, layer < 2 ? 1 : 0);
  }

  hipMemsetAsync(sums, 0, N_GRAPHS * EMB * sizeof(float), stream);
  hipMemsetAsync(counts, 0, N_GRAPHS * sizeof(float), stream);
  k_pool<<<(N_NODES + 31) / 32, 128, 0, stream>>>(h, batch, sums, counts);
  k_head<<<N_GRAPHS, 128, 0, stream>>>(sums, counts, fc1_w, fc1_b, fc2_w, fc2_b, out);
}